// Round 1
// baseline (147.587 us; speedup 1.0000x reference)
//
#include <hip/hip_runtime.h>

#define IH 4096
#define IW 4096
#define KH 7
#define KW 7
#define OH 4090
#define OW 4090

// Block: 256 threads = 64 (x) × 4 (y). Block tile: 256 wide × 32 tall outputs.
// Thread micro-tile: 4 wide × 8 tall = 32 outputs.
// Grid: ceil(4090/256)=16 × ceil(4090/32)=128.
__global__ __launch_bounds__(256) void conv7x7_kernel(
    const float* __restrict__ x,
    const float* __restrict__ w,
    const float* __restrict__ bias,
    float* __restrict__ out)
{
    const int tid = threadIdx.x;
    const int tx  = tid & 63;   // 0..63  (x position within block tile)
    const int ty  = tid >> 6;   // 0..3   (y band within block tile)
    const int ox0 = blockIdx.x * 256 + tx * 4;
    const int oy0 = blockIdx.y * 32  + ty * 8;

    // Weights are wave-uniform -> compiler emits s_load, lives in SGPRs.
    float wt[KH * KW];
#pragma unroll
    for (int k = 0; k < KH * KW; ++k) wt[k] = w[k];
    const float b = bias[0];

    float acc[8][4];
#pragma unroll
    for (int r = 0; r < 8; ++r)
#pragma unroll
        for (int c = 0; c < 4; ++c) acc[r][c] = b;

    // Vector path valid when all 10 input columns ox0..ox0+9 are in-bounds.
    const bool xvec = (ox0 + 9) < IW;

#pragma unroll
    for (int ir = 0; ir < 14; ++ir) {
        int iy = oy0 + ir;
        iy = iy < IH ? iy : IH - 1;           // clamp: only affects invalid outputs
        const float* xr = x + (size_t)iy * IW;

        float r[10];
        if (xvec) {
            const float4 q0 = *(const float4*)(xr + ox0);       // 16B aligned
            const float4 q1 = *(const float4*)(xr + ox0 + 4);
            const float2 q2 = *(const float2*)(xr + ox0 + 8);
            r[0] = q0.x; r[1] = q0.y; r[2] = q0.z; r[3] = q0.w;
            r[4] = q1.x; r[5] = q1.y; r[6] = q1.z; r[7] = q1.w;
            r[8] = q2.x; r[9] = q2.y;
        } else {
#pragma unroll
            for (int j = 0; j < 10; ++j) {
                int ix = ox0 + j;
                ix = ix < IW ? ix : IW - 1;   // clamp: only affects invalid outputs
                r[j] = xr[ix];
            }
        }

#pragma unroll
        for (int ky = 0; ky < KH; ++ky) {
            const int ry = ir - ky;           // output row fed by this input row
            if (ry >= 0 && ry < 8) {          // folded at compile time (full unroll)
#pragma unroll
                for (int kx = 0; kx < KW; ++kx) {
                    const float wv = wt[ky * KW + kx];
#pragma unroll
                    for (int c = 0; c < 4; ++c)
                        acc[ry][c] += wv * r[kx + c];
                }
            }
        }
    }

    // Stores: rows of `out` are 4090 floats -> only 8B alignment guaranteed
    // (index oy*4090+ox0 is always even). Use float2 pairs; scalar at right edge.
#pragma unroll
    for (int ry = 0; ry < 8; ++ry) {
        const int oy = oy0 + ry;
        if (oy < OH) {
            float* orow = out + (size_t)oy * OW;
            if (ox0 + 3 < OW) {
                *(float2*)(orow + ox0)     = make_float2(acc[ry][0], acc[ry][1]);
                *(float2*)(orow + ox0 + 2) = make_float2(acc[ry][2], acc[ry][3]);
            } else {
#pragma unroll
                for (int c = 0; c < 4; ++c)
                    if (ox0 + c < OW) orow[ox0 + c] = acc[ry][c];
            }
        }
    }
}

extern "C" void kernel_launch(void* const* d_in, const int* in_sizes, int n_in,
                              void* d_out, int out_size, void* d_ws, size_t ws_size,
                              hipStream_t stream) {
    const float* x    = (const float*)d_in[0];
    const float* w    = (const float*)d_in[1];
    const float* bias = (const float*)d_in[2];
    float* out        = (float*)d_out;

    dim3 grid((OW + 255) / 256, (OH + 31) / 32);   // 16 x 128
    conv7x7_kernel<<<grid, dim3(256), 0, stream>>>(x, w, bias, out);
}